// Round 1
// baseline (6851.927 us; speedup 1.0000x reference)
//
#include <hip/hip_runtime.h>

// LSTM persistent-kernel implementation for MI355X (gfx950).
// B=64, T=512, D=512, U=1024. Recurrence runs in ONE cooperative kernel:
// 256 blocks (1/CU), each owns 4 hidden units (16 gate columns).
// W slice (Wx;Wh = [1536 x 16]) pre-swizzled to fp16 in LDS (48 KB).
// h broadcast via double-buffered fp16 global buffer + per-step grid barrier.

#define TT 512
#define BB 64
#define DD 512
#define UUNITS 1024
#define G4 4096          // 4*U
#define NBLK 256
#define KTOT 1536        // DD + UUNITS
#define NKB_X 16         // DD/32
#define NKB_H 32         // UUNITS/32

typedef _Float16 f16x8 __attribute__((ext_vector_type(8)));
typedef _Float16 f16x4 __attribute__((ext_vector_type(4)));
typedef float f32x4 __attribute__((ext_vector_type(4)));

__device__ __forceinline__ float sigmoidf_fast(float x) {
  return 1.0f / (1.0f + __expf(-x));
}
__device__ __forceinline__ float tanhf_fast(float x) {
  x = fminf(fmaxf(x, -15.0f), 15.0f);   // avoid exp overflow -> NaN
  float e = __expf(2.0f * x);
  return (e - 1.0f) / (e + 1.0f);
}

// Pass 0: x (fp32) -> fp16, h0 (fp32) -> fp16 into h ping-pong buffer 0.
__global__ void convert_inputs(const float* __restrict__ x,
                               const float* __restrict__ h0,
                               _Float16* __restrict__ x16,
                               _Float16* __restrict__ h16) {
  int i = blockIdx.x * blockDim.x + threadIdx.x;
  int stride = gridDim.x * blockDim.x;
  const int n4 = BB * TT * DD / 4;
  const float4* x4 = (const float4*)x;
  for (int idx = i; idx < n4; idx += stride) {
    float4 v = x4[idx];
    f16x4 o;
    o[0] = (_Float16)v.x; o[1] = (_Float16)v.y;
    o[2] = (_Float16)v.z; o[3] = (_Float16)v.w;
    *(f16x4*)(x16 + (size_t)idx * 4) = o;
  }
  if (i < BB * UUNITS) h16[i] = (_Float16)h0[i];
}

__global__ __launch_bounds__(256, 1) void lstm_persistent(
    const _Float16* __restrict__ x16,   // [B,T,D] fp16
    const float* __restrict__ c0,       // [B,U]
    const float* __restrict__ Wx,       // [D,4U] fp32
    const float* __restrict__ Wh,       // [U,4U] fp32
    const float* __restrict__ b,        // [4U]
    _Float16* __restrict__ h_bufs,      // 2 x [B,U] fp16 ping-pong
    float* __restrict__ out,            // [B,U] fp32
    int* __restrict__ counter)          // grid barrier (monotonic)
{
  // B-fragment-swizzled W slice: for k-block kb, lane L, 8 contiguous fp16.
  // element (k, n) at [ (k>>5)*512 + ((k>>3)&3)*128 + n*8 + (k&7) ]
  __shared__ _Float16 Blds[KTOT / 32 * 512];   // 48*512*2 = 49152 B
  __shared__ float gtile[4 * 256];             // 4 KB, wave-private 16x16 tiles

  const int wg   = blockIdx.x;       // 0..255 -> owns u = wg*4 .. wg*4+3
  const int tid  = threadIdx.x;
  const int wave = tid >> 6;         // 0..3 -> batches wave*16..wave*16+15
  const int lane = tid & 63;
  const int quad = lane >> 4;        // 0..3
  const int ncol = lane & 15;        // MFMA col (local gate column)
  const int u0   = wg * 4;

  // ---- stage W slice into LDS, fp16, B-fragment order ----
  // local col n = uu*4 + gate  -> global col c = gate*1024 + u0 + uu
  for (int i = 0; i < 24; ++i) {
    int idx = i * 256 + tid;                 // 0..6143 = (k, gate) pairs
    int gate = idx & 3;
    int k = idx >> 2;                        // 0..1535
    const float* src = (k < DD) ? (Wx + (size_t)k * G4)
                                : (Wh + (size_t)(k - DD) * G4);
    float4 v = *(const float4*)(src + gate * 1024 + u0);  // uu = 0..3
    int base = (k >> 5) * 512 + ((k >> 3) & 3) * 128 + (k & 7);
    Blds[base + (0 * 4 + gate) * 8] = (_Float16)v.x;
    Blds[base + (1 * 4 + gate) * 8] = (_Float16)v.y;
    Blds[base + (2 * 4 + gate) * 8] = (_Float16)v.z;
    Blds[base + (3 * 4 + gate) * 8] = (_Float16)v.w;
  }

  // bias for this lane's gate column (same for all 4 acc rows)
  const int gcol = (ncol & 3) * 1024 + u0 + (ncol >> 2);
  const float bias = b[gcol];

  // c-state: one value per lane. lane -> (b_local = lane>>2, uu = lane&3)
  const int b_idx = wave * 16 + (lane >> 2);
  const int u_idx = u0 + (lane & 3);
  float c_st = c0[b_idx * UUNITS + u_idx];

  __syncthreads();

  const int arow = wave * 16 + ncol;   // A-operand row (batch), m = lane&15
  const _Float16* xbase = x16 + ((size_t)arow * TT) * DD + quad * 8;
  float* gt = &gtile[wave * 256];

  for (int t = 0; t < TT; ++t) {
    f32x4 acc  = {bias, bias, bias, bias};
    f32x4 acc2 = {0.f, 0.f, 0.f, 0.f};

    // ---- x-part (independent of h) : K = 0..511 ----
    const _Float16* xrow = xbase + (size_t)t * DD;
#pragma unroll
    for (int kb = 0; kb < NKB_X; kb += 2) {
      f16x8 a0 = *(const f16x8*)(xrow + kb * 32);
      f16x8 b0 = *(const f16x8*)(&Blds[kb * 512 + quad * 128 + ncol * 8]);
      acc = __builtin_amdgcn_mfma_f32_16x16x32_f16(a0, b0, acc, 0, 0, 0);
      f16x8 a1 = *(const f16x8*)(xrow + (kb + 1) * 32);
      f16x8 b1 = *(const f16x8*)(&Blds[(kb + 1) * 512 + quad * 128 + ncol * 8]);
      acc2 = __builtin_amdgcn_mfma_f32_16x16x32_f16(a1, b1, acc2, 0, 0, 0);
    }

    // ---- wait for h(t) (all blocks wrote it at end of step t-1) ----
    if (t > 0) {
      if (tid == 0) {
        const int target = t * NBLK;
        while (__hip_atomic_load(counter, __ATOMIC_RELAXED,
                                 __HIP_MEMORY_SCOPE_AGENT) < target)
          __builtin_amdgcn_s_sleep(1);
        __builtin_amdgcn_fence(__ATOMIC_ACQUIRE, "agent");  // inv L1/L2
      }
      __syncthreads();
    }

    // ---- h-part : K = 512..1535 ----
    const _Float16* hrow =
        h_bufs + (size_t)(t & 1) * BB * UUNITS + (size_t)arow * UUNITS + quad * 8;
#pragma unroll
    for (int kb = 0; kb < NKB_H; kb += 2) {
      f16x8 a0 = *(const f16x8*)(hrow + kb * 32);
      f16x8 b0 = *(const f16x8*)(&Blds[(NKB_X + kb) * 512 + quad * 128 + ncol * 8]);
      acc = __builtin_amdgcn_mfma_f32_16x16x32_f16(a0, b0, acc, 0, 0, 0);
      f16x8 a1 = *(const f16x8*)(hrow + (kb + 1) * 32);
      f16x8 b1 = *(const f16x8*)(&Blds[(NKB_X + kb + 1) * 512 + quad * 128 + ncol * 8]);
      acc2 = __builtin_amdgcn_mfma_f32_16x16x32_f16(a1, b1, acc2, 0, 0, 0);
    }
    acc += acc2;

    // ---- epilogue: re-layout gates via wave-private LDS tile ----
    // C layout: row = quad*4+reg, col = ncol. gtile[row*16 + col].
#pragma unroll
    for (int r = 0; r < 4; ++r)
      gt[(quad * 4 + r) * 16 + ncol] = acc[r];
    // lane reads its (b_local, uu): cols uu*4 + {0,1,2,3} = {i,f,g,o}
    float4 g4v = *(const float4*)&gt[(lane >> 2) * 16 + (lane & 3) * 4];
    float ig = sigmoidf_fast(g4v.x);
    float fg = sigmoidf_fast(g4v.y);
    float gg = tanhf_fast(g4v.z);
    float og = sigmoidf_fast(g4v.w);
    float cn = fg * c_st + ig * gg;
    c_st = cn;
    float hn = og * tanhf_fast(cn);

    _Float16* hw = h_bufs + (size_t)((t + 1) & 1) * BB * UUNITS;
    hw[b_idx * UUNITS + u_idx] = (_Float16)hn;
    if (t == TT - 1) out[b_idx * UUNITS + u_idx] = hn;

    // ---- arrive (release: flush h stores to coherent point) ----
    if (t + 1 < TT) {
      __syncthreads();   // all waves' h stores complete before arrival
      if (tid == 0)
        __hip_atomic_fetch_add(counter, 1, __ATOMIC_RELEASE,
                               __HIP_MEMORY_SCOPE_AGENT);
    }
  }
}

extern "C" void kernel_launch(void* const* d_in, const int* in_sizes, int n_in,
                              void* d_out, int out_size, void* d_ws, size_t ws_size,
                              hipStream_t stream) {
  const float* x  = (const float*)d_in[0];
  const float* h0 = (const float*)d_in[1];
  const float* c0 = (const float*)d_in[2];
  const float* Wx = (const float*)d_in[3];
  const float* Wh = (const float*)d_in[4];
  const float* b  = (const float*)d_in[5];
  float* out = (float*)d_out;

  char* ws = (char*)d_ws;
  _Float16* x16  = (_Float16*)ws;                                  // 32 MB
  _Float16* hbuf = (_Float16*)(ws + (size_t)BB * TT * DD * 2);     // 256 KB
  int* counter   = (int*)(ws + (size_t)BB * TT * DD * 2
                             + (size_t)2 * BB * UUNITS * 2);

  hipMemsetAsync(counter, 0, 128, stream);
  hipLaunchKernelGGL(convert_inputs, dim3(1024), dim3(256), 0, stream,
                     x, h0, x16, hbuf);

  static void* args[8];
  args[0] = (void*)&x16;  args[1] = (void*)&c0;  args[2] = (void*)&Wx;
  args[3] = (void*)&Wh;   args[4] = (void*)&b;   args[5] = (void*)&hbuf;
  args[6] = (void*)&out;  args[7] = (void*)&counter;
  hipLaunchCooperativeKernel((void*)lstm_persistent, dim3(NBLK), dim3(256),
                             args, 0, stream);
}